// Round 5
// baseline (497.944 us; speedup 1.0000x reference)
//
#include <hip/hip_runtime.h>
#include <math.h>

#define DDIM 1024
#define NH 16
#define HDIM 64
#define SCALE 0.125f
#define DLAM -0.1f
#define LNEPS 1e-5f
#define NS 32
#define RPB 128  // rows (n) per flash block (= N/NS)

__device__ inline float dot4(float4 a, float4 b) {
    return fmaf(a.x, b.x, fmaf(a.y, b.y, fmaf(a.z, b.z, a.w * b.w)));
}

// K1: q[b,c] = query[b,:] @ Wq[:,c] + bq[c]; grid (B,8), 512 thr, 4-way d-split
__global__ __launch_bounds__(512) void k_q(const float* __restrict__ query,
                                           const float* __restrict__ Wq,
                                           const float* __restrict__ bq,
                                           float* __restrict__ qout) {
    int b = blockIdx.x, c0 = blockIdx.y * 128;
    __shared__ float qs[DDIM];
    __shared__ float ps[512];
    int t = threadIdx.x;
    for (int i = t; i < DDIM; i += 512) qs[i] = query[b * DDIM + i];
    __syncthreads();
    int cl = t & 127;
    int col = c0 + cl;
    int d0 = (t >> 7) * 256;
    float acc = 0.f;
#pragma unroll 8
    for (int d = d0; d < d0 + 256; ++d)
        acc = fmaf(qs[d], Wq[(size_t)d * DDIM + col], acc);
    ps[t] = acc;
    __syncthreads();
    if (t < 128)
        qout[b * DDIM + col] = ps[t] + ps[t + 128] + ps[t + 256] + ps[t + 384] + bq[col];
}

// K2: qp[b,h,d] = SCALE * sum_j Wk[d, h*64+j] * q[b, h*64+j]
__global__ __launch_bounds__(256) void k_qp(const float* __restrict__ qin,
                                            const float* __restrict__ Wk,
                                            float* __restrict__ qp) {
    int b = blockIdx.x, dt = blockIdx.y;
    __shared__ float qs[DDIM];
    for (int i = threadIdx.x; i < DDIM; i += 256) qs[i] = qin[b * DDIM + i];
    __syncthreads();
    int h = threadIdx.x & 15, dl = threadIdx.x >> 4;
    int d = dt * 16 + dl;
    const float* wr = Wk + (size_t)d * DDIM + h * HDIM;
    const float* qh = qs + h * HDIM;
    float acc = 0.f;
#pragma unroll
    for (int j = 0; j < HDIM; ++j) acc = fmaf(wr[j], qh[j], acc);
    qp[((size_t)(b * NH + h)) * DDIM + d] = acc * SCALE;
}

// K2b: sb[b,h] = SCALE * sum_j bk[h*64+j] * q[b, h*64+j]
__global__ __launch_bounds__(512) void k_sb(const float* __restrict__ qin,
                                            const float* __restrict__ bk,
                                            float* __restrict__ sb) {
    int idx = threadIdx.x;
    int b = idx >> 4, h = idx & 15;
    float acc = 0.f;
#pragma unroll
    for (int j = 0; j < HDIM; ++j)
        acc = fmaf(bk[h * HDIM + j], qin[b * DDIM + h * HDIM + j], acc);
    sb[idx] = acc * SCALE;
}

// K3: fused flash pass. 512 thr = 8 waves x 2 heads. ctx read once.
// Mask folded into dls: masked rows get -1e30 bias (handled by online rescale / k_comb).
__global__ __launch_bounds__(512) void k_flash(const float* __restrict__ ctx,
                                               const float* __restrict__ qp,
                                               const float* __restrict__ sb,
                                               const float* __restrict__ dist,
                                               const int* __restrict__ mask,
                                               float* __restrict__ partA,
                                               float* __restrict__ partM,
                                               float* __restrict__ partL, int N) {
    int b = blockIdx.x, ns = blockIdx.y;
    int nbase = ns * RPB;
    __shared__ float dls[RPB];
    int t = threadIdx.x;
    if (t < RPB) {
        float dv = dist[(size_t)b * N + nbase + t] * DLAM;
        dls[t] = mask[(size_t)b * N + nbase + t] ? dv : -1e30f;
    }
    __syncthreads();

    int lane = t & 63, w = t >> 6;
    int h0 = w * 2;
    float4 qr[2][4];
    float sbr[2];
#pragma unroll
    for (int hh = 0; hh < 2; ++hh) {
        const float4* p = reinterpret_cast<const float4*>(
            qp + ((size_t)(b * NH + h0 + hh)) * DDIM + lane * 16);
        qr[hh][0] = p[0]; qr[hh][1] = p[1]; qr[hh][2] = p[2]; qr[hh][3] = p[3];
        sbr[hh] = sb[b * NH + h0 + hh];
    }

    float m[2] = {-1e30f, -1e30f}, l[2] = {0.f, 0.f};
    float4 acc[2][4];
#pragma unroll
    for (int hh = 0; hh < 2; ++hh)
#pragma unroll
        for (int k = 0; k < 4; ++k) acc[hh][k] = make_float4(0.f, 0.f, 0.f, 0.f);

    const float* rowp = ctx + ((size_t)b * N + nbase) * DDIM + lane * 16;
    for (int r = 0; r < RPB; ++r) {
        const float4* c = reinterpret_cast<const float4*>(rowp);
        float4 c0 = c[0], c1 = c[1], c2 = c[2], c3 = c[3];
        float p0 = dot4(c0, qr[0][0]) + dot4(c1, qr[0][1]) +
                   dot4(c2, qr[0][2]) + dot4(c3, qr[0][3]);
        float p1 = dot4(c0, qr[1][0]) + dot4(c1, qr[1][1]) +
                   dot4(c2, qr[1][2]) + dot4(c3, qr[1][3]);
#pragma unroll
        for (int off = 32; off > 0; off >>= 1) {
            p0 += __shfl_xor(p0, off, 64);
            p1 += __shfl_xor(p1, off, 64);
        }
        float dv = dls[r];
        float pv[2] = {p0, p1};
#pragma unroll
        for (int hh = 0; hh < 2; ++hh) {
            float s = pv[hh] + sbr[hh] + dv;
            if (__any(s - m[hh] > 8.f)) {
                float f = __expf(m[hh] - s);
                l[hh] *= f;
#pragma unroll
                for (int k = 0; k < 4; ++k) {
                    acc[hh][k].x *= f; acc[hh][k].y *= f;
                    acc[hh][k].z *= f; acc[hh][k].w *= f;
                }
                m[hh] = s;
            }
            float e = __expf(s - m[hh]);
            l[hh] += e;
            acc[hh][0].x = fmaf(e, c0.x, acc[hh][0].x);
            acc[hh][0].y = fmaf(e, c0.y, acc[hh][0].y);
            acc[hh][0].z = fmaf(e, c0.z, acc[hh][0].z);
            acc[hh][0].w = fmaf(e, c0.w, acc[hh][0].w);
            acc[hh][1].x = fmaf(e, c1.x, acc[hh][1].x);
            acc[hh][1].y = fmaf(e, c1.y, acc[hh][1].y);
            acc[hh][1].z = fmaf(e, c1.z, acc[hh][1].z);
            acc[hh][1].w = fmaf(e, c1.w, acc[hh][1].w);
            acc[hh][2].x = fmaf(e, c2.x, acc[hh][2].x);
            acc[hh][2].y = fmaf(e, c2.y, acc[hh][2].y);
            acc[hh][2].z = fmaf(e, c2.z, acc[hh][2].z);
            acc[hh][2].w = fmaf(e, c2.w, acc[hh][2].w);
            acc[hh][3].x = fmaf(e, c3.x, acc[hh][3].x);
            acc[hh][3].y = fmaf(e, c3.y, acc[hh][3].y);
            acc[hh][3].z = fmaf(e, c3.z, acc[hh][3].z);
            acc[hh][3].w = fmaf(e, c3.w, acc[hh][3].w);
        }
        rowp += DDIM;
    }

#pragma unroll
    for (int hh = 0; hh < 2; ++hh) {
        float* dst = partA + ((size_t)((b * NS + ns) * NH + h0 + hh)) * DDIM + lane * 16;
#pragma unroll
        for (int k = 0; k < 4; ++k)
            *reinterpret_cast<float4*>(dst + k * 4) = acc[hh][k];
    }
    if (lane == 0) {
#pragma unroll
        for (int hh = 0; hh < 2; ++hh) {
            int idx = (b * NS + ns) * NH + h0 + hh;
            partM[idx] = m[hh];
            partL[idx] = l[hh];
        }
    }
}

// K4: merge chunk partials -> ctxa[b,h,d]
__global__ __launch_bounds__(256) void k_comb(const float* __restrict__ partA,
                                              const float* __restrict__ partM,
                                              const float* __restrict__ partL,
                                              float* __restrict__ ctxa) {
    int row = blockIdx.x;  // b*NH + h
    int b = row >> 4, h = row & 15;
    float M = -1e30f;
#pragma unroll
    for (int ns = 0; ns < NS; ++ns)
        M = fmaxf(M, partM[(b * NS + ns) * NH + h]);
    float denom = 0.f;
#pragma unroll
    for (int ns = 0; ns < NS; ++ns)
        denom = fmaf(__expf(partM[(b * NS + ns) * NH + h] - M),
                     partL[(b * NS + ns) * NH + h], denom);
    float inv = 1.f / denom;
    int d4 = threadIdx.x * 4;
    float4 a = make_float4(0.f, 0.f, 0.f, 0.f);
#pragma unroll 8
    for (int ns = 0; ns < NS; ++ns) {
        float wv = __expf(partM[(b * NS + ns) * NH + h] - M);
        float4 v = *reinterpret_cast<const float4*>(
            partA + ((size_t)((b * NS + ns) * NH + h)) * DDIM + d4);
        a.x = fmaf(wv, v.x, a.x);
        a.y = fmaf(wv, v.y, a.y);
        a.z = fmaf(wv, v.z, a.z);
        a.w = fmaf(wv, v.w, a.w);
    }
    float4 o = make_float4(a.x * inv, a.y * inv, a.z * inv, a.w * inv);
    *reinterpret_cast<float4*>(ctxa + (size_t)row * DDIM + d4) = o;
}

// K5: fused epilogue: oattn = ctxa.Wv+bv ; x = query + oattn.Wo+bo ; out = LN(x)
__global__ __launch_bounds__(512) void k_epi(const float* __restrict__ ctxa,
                                             const float* __restrict__ Wv,
                                             const float* __restrict__ bv,
                                             const float* __restrict__ Wo,
                                             const float* __restrict__ bo,
                                             const float* __restrict__ query,
                                             const float* __restrict__ gamma,
                                             const float* __restrict__ beta,
                                             float* __restrict__ out) {
    int b = blockIdx.x, t = threadIdx.x;
    __shared__ float cs[NH * DDIM];   // 64 KB
    __shared__ float vec[DDIM];
    __shared__ float xs[DDIM];
    __shared__ float ps[4][2][256];   // 8 KB
    __shared__ float red[16];
    for (int i = t; i < NH * DDIM; i += 512)
        cs[i] = ctxa[(size_t)b * NH * DDIM + i];
    __syncthreads();

    int cl = t & 255, dh = t >> 8;
    // ---- vproj ----
    {
        int c0 = cl, c1 = cl + 256, c2 = cl + 512, c3 = cl + 768;
        const float* r0 = cs + (c0 >> 6) * DDIM;
        const float* r1 = cs + (c1 >> 6) * DDIM;
        const float* r2 = cs + (c2 >> 6) * DDIM;
        const float* r3 = cs + (c3 >> 6) * DDIM;
        float a0 = 0.f, a1 = 0.f, a2 = 0.f, a3 = 0.f;
#pragma unroll 4
        for (int d = dh * 512; d < dh * 512 + 512; ++d) {
            const float* wr = Wv + (size_t)d * DDIM;
            a0 = fmaf(r0[d], wr[c0], a0);
            a1 = fmaf(r1[d], wr[c1], a1);
            a2 = fmaf(r2[d], wr[c2], a2);
            a3 = fmaf(r3[d], wr[c3], a3);
        }
        ps[0][dh][cl] = a0; ps[1][dh][cl] = a1;
        ps[2][dh][cl] = a2; ps[3][dh][cl] = a3;
    }
    __syncthreads();
    if (t < 256) {
#pragma unroll
        for (int k = 0; k < 4; ++k)
            vec[t + k * 256] = ps[k][0][t] + ps[k][1][t] + bv[t + k * 256];
    }
    __syncthreads();
    // ---- oproj + residual ----
    {
        int c0 = cl, c1 = cl + 256, c2 = cl + 512, c3 = cl + 768;
        float a0 = 0.f, a1 = 0.f, a2 = 0.f, a3 = 0.f;
#pragma unroll 4
        for (int d = dh * 512; d < dh * 512 + 512; ++d) {
            float ov = vec[d];
            const float* wr = Wo + (size_t)d * DDIM;
            a0 = fmaf(ov, wr[c0], a0);
            a1 = fmaf(ov, wr[c1], a1);
            a2 = fmaf(ov, wr[c2], a2);
            a3 = fmaf(ov, wr[c3], a3);
        }
        ps[0][dh][cl] = a0; ps[1][dh][cl] = a1;
        ps[2][dh][cl] = a2; ps[3][dh][cl] = a3;
    }
    __syncthreads();
    if (t < 256) {
#pragma unroll
        for (int k = 0; k < 4; ++k) {
            int c = t + k * 256;
            xs[c] = query[b * DDIM + c] + ps[k][0][t] + ps[k][1][t] + bo[c];
        }
    }
    __syncthreads();
    // ---- LayerNorm (512 thr, 2 elems each) ----
    float x0 = xs[t], x1 = xs[t + 512];
    float lsum = x0 + x1;
#pragma unroll
    for (int off = 32; off > 0; off >>= 1) lsum += __shfl_xor(lsum, off, 64);
    if ((t & 63) == 0) red[t >> 6] = lsum;
    __syncthreads();
    float mu = 0.f;
#pragma unroll
    for (int w = 0; w < 8; ++w) mu += red[w];
    mu *= (1.f / DDIM);
    float d0 = x0 - mu, d1 = x1 - mu;
    float lsq = d0 * d0 + d1 * d1;
#pragma unroll
    for (int off = 32; off > 0; off >>= 1) lsq += __shfl_xor(lsq, off, 64);
    if ((t & 63) == 0) red[8 + (t >> 6)] = lsq;
    __syncthreads();
    float var = 0.f;
#pragma unroll
    for (int w = 0; w < 8; ++w) var += red[8 + w];
    var *= (1.f / DDIM);
    float rstd = rsqrtf(var + LNEPS);
    out[b * DDIM + t] = d0 * rstd * gamma[t] + beta[t];
    out[b * DDIM + t + 512] = d1 * rstd * gamma[t + 512] + beta[t + 512];
}

extern "C" void kernel_launch(void* const* d_in, const int* in_sizes, int n_in,
                              void* d_out, int out_size, void* d_ws, size_t ws_size,
                              hipStream_t stream) {
    const float* query = (const float*)d_in[0];
    const float* ctx   = (const float*)d_in[1];
    const float* dist  = (const float*)d_in[2];
    const int*   mask  = (const int*)d_in[3];
    const float* Wq = (const float*)d_in[4];
    const float* bq = (const float*)d_in[5];
    const float* Wk = (const float*)d_in[6];
    const float* bk = (const float*)d_in[7];
    const float* Wv = (const float*)d_in[8];
    const float* bv = (const float*)d_in[9];
    const float* Wo = (const float*)d_in[10];
    const float* bo = (const float*)d_in[11];
    const float* gamma = (const float*)d_in[12];
    const float* beta  = (const float*)d_in[13];
    float* out = (float*)d_out;

    int B = in_sizes[0] / DDIM;        // 32
    int N = in_sizes[1] / (B * DDIM);  // 4096

    float* ws = (float*)d_ws;
    float* q      = ws;                                   // B*D
    float* qp     = q + (size_t)B * DDIM;                 // B*H*D
    float* sb     = qp + (size_t)B * NH * DDIM;           // B*H
    float* partA  = sb + (size_t)B * NH;                  // B*NS*H*D
    float* partM  = partA + (size_t)B * NS * NH * DDIM;   // B*NS*H
    float* partL  = partM + (size_t)B * NS * NH;          // B*NS*H
    float* ctxa   = partL + (size_t)B * NS * NH;          // B*H*D

    k_q<<<dim3(B, 8), 512, 0, stream>>>(query, Wq, bq, q);
    k_qp<<<dim3(B, DDIM / 16), 256, 0, stream>>>(q, Wk, qp);
    k_sb<<<1, B * NH, 0, stream>>>(q, bk, sb);
    k_flash<<<dim3(B, NS), 512, 0, stream>>>(ctx, qp, sb, dist, mask,
                                             partA, partM, partL, N);
    k_comb<<<B * NH, 256, 0, stream>>>(partA, partM, partL, ctxa);
    k_epi<<<B, 512, 0, stream>>>(ctxa, Wv, bv, Wo, bo, query, gamma, beta, out);
}

// Round 6
// 491.083 us; speedup vs baseline: 1.0140x; 1.0140x over previous
//
#include <hip/hip_runtime.h>
#include <math.h>

#define DDIM 1024
#define NH 16
#define HDIM 64
#define SCALE 0.125f
#define DLAM -0.1f
#define LNEPS 1e-5f
#define NS 32
#define RPB 128  // rows (n) per flash block (= N/NS)

__device__ inline float dot4(float4 a, float4 b) {
    return fmaf(a.x, b.x, fmaf(a.y, b.y, fmaf(a.z, b.z, a.w * b.w)));
}

// K1: q[b,c] = query[b,:] @ Wq[:,c] + bq[c]; grid (B,8), 512 thr, 4-way d-split
__global__ __launch_bounds__(512) void k_q(const float* __restrict__ query,
                                           const float* __restrict__ Wq,
                                           const float* __restrict__ bq,
                                           float* __restrict__ qout) {
    int b = blockIdx.x, c0 = blockIdx.y * 128;
    __shared__ float qs[DDIM];
    __shared__ float ps[512];
    int t = threadIdx.x;
    for (int i = t; i < DDIM; i += 512) qs[i] = query[b * DDIM + i];
    __syncthreads();
    int cl = t & 127;
    int col = c0 + cl;
    int d0 = (t >> 7) * 256;
    float acc = 0.f;
#pragma unroll 8
    for (int d = d0; d < d0 + 256; ++d)
        acc = fmaf(qs[d], Wq[(size_t)d * DDIM + col], acc);
    ps[t] = acc;
    __syncthreads();
    if (t < 128)
        qout[b * DDIM + col] = ps[t] + ps[t + 128] + ps[t + 256] + ps[t + 384] + bq[col];
}

// K2: qp[b,h,d] = SCALE * sum_j Wk[d, h*64+j] * q[b, h*64+j]
__global__ __launch_bounds__(256) void k_qp(const float* __restrict__ qin,
                                            const float* __restrict__ Wk,
                                            float* __restrict__ qp) {
    int b = blockIdx.x, dt = blockIdx.y;
    __shared__ float qs[DDIM];
    for (int i = threadIdx.x; i < DDIM; i += 256) qs[i] = qin[b * DDIM + i];
    __syncthreads();
    int h = threadIdx.x & 15, dl = threadIdx.x >> 4;
    int d = dt * 16 + dl;
    const float* wr = Wk + (size_t)d * DDIM + h * HDIM;
    const float* qh = qs + h * HDIM;
    float acc = 0.f;
#pragma unroll
    for (int j = 0; j < HDIM; ++j) acc = fmaf(wr[j], qh[j], acc);
    qp[((size_t)(b * NH + h)) * DDIM + d] = acc * SCALE;
}

// K2b: sb[b,h] = SCALE * sum_j bk[h*64+j] * q[b, h*64+j]
__global__ __launch_bounds__(512) void k_sb(const float* __restrict__ qin,
                                            const float* __restrict__ bk,
                                            float* __restrict__ sb) {
    int idx = threadIdx.x;
    int b = idx >> 4, h = idx & 15;
    float acc = 0.f;
#pragma unroll
    for (int j = 0; j < HDIM; ++j)
        acc = fmaf(bk[h * HDIM + j], qin[b * DDIM + h * HDIM + j], acc);
    sb[idx] = acc * SCALE;
}

// K3: flash pass. grid (B, NS, 2). 256 thr = 4 waves x 2 heads (heads hg*8+w*2..+1).
// 2-row unroll for load ILP; paired butterfly (8 shfl / row-pair / head).
__global__ __launch_bounds__(256) void k_flash(const float* __restrict__ ctx,
                                               const float* __restrict__ qp,
                                               const float* __restrict__ sb,
                                               const float* __restrict__ dist,
                                               const int* __restrict__ mask,
                                               float* __restrict__ partA,
                                               float* __restrict__ partM,
                                               float* __restrict__ partL, int N) {
    int b = blockIdx.x, ns = blockIdx.y, hg = blockIdx.z;
    int nbase = ns * RPB;
    __shared__ float dls[RPB];
    int t = threadIdx.x;
    if (t < RPB) {
        float dv = dist[(size_t)b * N + nbase + t] * DLAM;
        dls[t] = mask[(size_t)b * N + nbase + t] ? dv : -1e30f;
    }
    __syncthreads();

    int lane = t & 63, w = t >> 6;
    int h0 = hg * 8 + w * 2;
    float4 qr[2][4];
    float sbr[2];
#pragma unroll
    for (int hh = 0; hh < 2; ++hh) {
        const float4* p = reinterpret_cast<const float4*>(
            qp + ((size_t)(b * NH + h0 + hh)) * DDIM + lane * 16);
        qr[hh][0] = p[0]; qr[hh][1] = p[1]; qr[hh][2] = p[2]; qr[hh][3] = p[3];
        sbr[hh] = sb[b * NH + h0 + hh];
    }

    float m[2] = {-1e30f, -1e30f}, l[2] = {0.f, 0.f};
    float4 acc[2][4];
#pragma unroll
    for (int hh = 0; hh < 2; ++hh)
#pragma unroll
        for (int k = 0; k < 4; ++k) acc[hh][k] = make_float4(0.f, 0.f, 0.f, 0.f);

    const float* rowp = ctx + ((size_t)b * N + nbase) * DDIM + lane * 16;
    for (int r = 0; r < RPB; r += 2) {
        const float4* cA = reinterpret_cast<const float4*>(rowp);
        const float4* cB = reinterpret_cast<const float4*>(rowp + DDIM);
        float4 a0 = cA[0], a1 = cA[1], a2 = cA[2], a3 = cA[3];
        float4 b0 = cB[0], b1 = cB[1], b2 = cB[2], b3 = cB[3];
        float pA[2], pB[2];
#pragma unroll
        for (int hh = 0; hh < 2; ++hh) {
            pA[hh] = dot4(a0, qr[hh][0]) + dot4(a1, qr[hh][1]) +
                     dot4(a2, qr[hh][2]) + dot4(a3, qr[hh][3]);
            pB[hh] = dot4(b0, qr[hh][0]) + dot4(b1, qr[hh][1]) +
                     dot4(b2, qr[hh][2]) + dot4(b3, qr[hh][3]);
        }
        // paired reduction: rows (A,B) together, 8 shfl per head
        float sAr[2], sBr[2];
#pragma unroll
        for (int hh = 0; hh < 2; ++hh) {
            float zA = pA[hh] + __shfl_xor(pA[hh], 32, 64);
            float zB = pB[hh] + __shfl_xor(pB[hh], 32, 64);
            float wv = (lane < 32) ? zA : zB;
            wv += __shfl_xor(wv, 16, 64);
            wv += __shfl_xor(wv, 8, 64);
            wv += __shfl_xor(wv, 4, 64);
            wv += __shfl_xor(wv, 2, 64);
            wv += __shfl_xor(wv, 1, 64);
            float uv = __shfl_xor(wv, 32, 64);
            sAr[hh] = (lane < 32) ? wv : uv;
            sBr[hh] = (lane < 32) ? uv : wv;
        }
        float dvA = dls[r], dvB = dls[r + 1];
#pragma unroll
        for (int hh = 0; hh < 2; ++hh) {
            // row A
            float s = sAr[hh] + sbr[hh] + dvA;
            if (__any(s - m[hh] > 8.f)) {
                float f = __expf(m[hh] - s);
                l[hh] *= f;
#pragma unroll
                for (int k = 0; k < 4; ++k) {
                    acc[hh][k].x *= f; acc[hh][k].y *= f;
                    acc[hh][k].z *= f; acc[hh][k].w *= f;
                }
                m[hh] = s;
            }
            float e = __expf(s - m[hh]);
            l[hh] += e;
            acc[hh][0].x = fmaf(e, a0.x, acc[hh][0].x);
            acc[hh][0].y = fmaf(e, a0.y, acc[hh][0].y);
            acc[hh][0].z = fmaf(e, a0.z, acc[hh][0].z);
            acc[hh][0].w = fmaf(e, a0.w, acc[hh][0].w);
            acc[hh][1].x = fmaf(e, a1.x, acc[hh][1].x);
            acc[hh][1].y = fmaf(e, a1.y, acc[hh][1].y);
            acc[hh][1].z = fmaf(e, a1.z, acc[hh][1].z);
            acc[hh][1].w = fmaf(e, a1.w, acc[hh][1].w);
            acc[hh][2].x = fmaf(e, a2.x, acc[hh][2].x);
            acc[hh][2].y = fmaf(e, a2.y, acc[hh][2].y);
            acc[hh][2].z = fmaf(e, a2.z, acc[hh][2].z);
            acc[hh][2].w = fmaf(e, a2.w, acc[hh][2].w);
            acc[hh][3].x = fmaf(e, a3.x, acc[hh][3].x);
            acc[hh][3].y = fmaf(e, a3.y, acc[hh][3].y);
            acc[hh][3].z = fmaf(e, a3.z, acc[hh][3].z);
            acc[hh][3].w = fmaf(e, a3.w, acc[hh][3].w);
            // row B
            s = sBr[hh] + sbr[hh] + dvB;
            if (__any(s - m[hh] > 8.f)) {
                float f = __expf(m[hh] - s);
                l[hh] *= f;
#pragma unroll
                for (int k = 0; k < 4; ++k) {
                    acc[hh][k].x *= f; acc[hh][k].y *= f;
                    acc[hh][k].z *= f; acc[hh][k].w *= f;
                }
                m[hh] = s;
            }
            e = __expf(s - m[hh]);
            l[hh] += e;
            acc[hh][0].x = fmaf(e, b0.x, acc[hh][0].x);
            acc[hh][0].y = fmaf(e, b0.y, acc[hh][0].y);
            acc[hh][0].z = fmaf(e, b0.z, acc[hh][0].z);
            acc[hh][0].w = fmaf(e, b0.w, acc[hh][0].w);
            acc[hh][1].x = fmaf(e, b1.x, acc[hh][1].x);
            acc[hh][1].y = fmaf(e, b1.y, acc[hh][1].y);
            acc[hh][1].z = fmaf(e, b1.z, acc[hh][1].z);
            acc[hh][1].w = fmaf(e, b1.w, acc[hh][1].w);
            acc[hh][2].x = fmaf(e, b2.x, acc[hh][2].x);
            acc[hh][2].y = fmaf(e, b2.y, acc[hh][2].y);
            acc[hh][2].z = fmaf(e, b2.z, acc[hh][2].z);
            acc[hh][2].w = fmaf(e, b2.w, acc[hh][2].w);
            acc[hh][3].x = fmaf(e, b3.x, acc[hh][3].x);
            acc[hh][3].y = fmaf(e, b3.y, acc[hh][3].y);
            acc[hh][3].z = fmaf(e, b3.z, acc[hh][3].z);
            acc[hh][3].w = fmaf(e, b3.w, acc[hh][3].w);
        }
        rowp += 2 * DDIM;
    }

#pragma unroll
    for (int hh = 0; hh < 2; ++hh) {
        float* dst = partA + ((size_t)((b * NS + ns) * NH + h0 + hh)) * DDIM + lane * 16;
#pragma unroll
        for (int k = 0; k < 4; ++k)
            *reinterpret_cast<float4*>(dst + k * 4) = acc[hh][k];
    }
    if (lane == 0) {
#pragma unroll
        for (int hh = 0; hh < 2; ++hh) {
            int idx = (b * NS + ns) * NH + h0 + hh;
            partM[idx] = m[hh];
            partL[idx] = l[hh];
        }
    }
}

// K4: merge chunk partials -> ctxa[b,h,d]
__global__ __launch_bounds__(256) void k_comb(const float* __restrict__ partA,
                                              const float* __restrict__ partM,
                                              const float* __restrict__ partL,
                                              float* __restrict__ ctxa) {
    int row = blockIdx.x;  // b*NH + h
    int b = row >> 4, h = row & 15;
    float M = -1e30f;
#pragma unroll
    for (int ns = 0; ns < NS; ++ns)
        M = fmaxf(M, partM[(b * NS + ns) * NH + h]);
    float denom = 0.f;
#pragma unroll
    for (int ns = 0; ns < NS; ++ns)
        denom = fmaf(__expf(partM[(b * NS + ns) * NH + h] - M),
                     partL[(b * NS + ns) * NH + h], denom);
    float inv = 1.f / denom;
    int d4 = threadIdx.x * 4;
    float4 a = make_float4(0.f, 0.f, 0.f, 0.f);
#pragma unroll 8
    for (int ns = 0; ns < NS; ++ns) {
        float wv = __expf(partM[(b * NS + ns) * NH + h] - M);
        float4 v = *reinterpret_cast<const float4*>(
            partA + ((size_t)((b * NS + ns) * NH + h)) * DDIM + d4);
        a.x = fmaf(wv, v.x, a.x);
        a.y = fmaf(wv, v.y, a.y);
        a.z = fmaf(wv, v.z, a.z);
        a.w = fmaf(wv, v.w, a.w);
    }
    float4 o = make_float4(a.x * inv, a.y * inv, a.z * inv, a.w * inv);
    *reinterpret_cast<float4*>(ctxa + (size_t)row * DDIM + d4) = o;
}

// K5: oattn[b,c] = ctxa[b, c>>6, :] . Wv[:, c] + bv[c]; grid (B, 8)
__global__ __launch_bounds__(256) void k_vproj(const float* __restrict__ ctxa,
                                               const float* __restrict__ Wv,
                                               const float* __restrict__ bv,
                                               float* __restrict__ oattn) {
    int b = blockIdx.x, c0 = blockIdx.y * 128;
    int h0 = c0 >> 6;
    __shared__ float cs[2][DDIM];
    __shared__ float ps[256];
    for (int i = threadIdx.x; i < 2 * DDIM; i += 256)
        cs[i >> 10][i & 1023] =
            ctxa[((size_t)(b * NH + h0 + (i >> 10))) * DDIM + (i & 1023)];
    __syncthreads();
    int t = threadIdx.x;
    int cl = t & 127;
    int col = c0 + cl;
    int hl = cl >> 6;
    int d0 = (t >> 7) * 512;
    float acc = 0.f;
#pragma unroll 8
    for (int d = d0; d < d0 + 512; ++d)
        acc = fmaf(cs[hl][d], Wv[(size_t)d * DDIM + col], acc);
    ps[t] = acc;
    __syncthreads();
    if (t < 128) oattn[b * DDIM + col] = ps[t] + ps[t + 128] + bv[col];
}

// K6: x[b,c] = query[b,c] + oattn[b,:] . Wo[:,c] + bo[c]; grid (B, 8)
__global__ __launch_bounds__(256) void k_oproj(const float* __restrict__ query,
                                               const float* __restrict__ oattn,
                                               const float* __restrict__ Wo,
                                               const float* __restrict__ bo,
                                               float* __restrict__ x) {
    int b = blockIdx.x, c0 = blockIdx.y * 128;
    __shared__ float os[DDIM];
    __shared__ float ps[256];
    for (int i = threadIdx.x; i < DDIM; i += 256) os[i] = oattn[b * DDIM + i];
    __syncthreads();
    int t = threadIdx.x;
    int col = c0 + (t & 127);
    int d0 = (t >> 7) * 512;
    float acc = 0.f;
#pragma unroll 8
    for (int d = d0; d < d0 + 512; ++d)
        acc = fmaf(os[d], Wo[(size_t)d * DDIM + col], acc);
    ps[t] = acc;
    __syncthreads();
    if (t < 128)
        x[b * DDIM + col] = query[b * DDIM + col] + ps[t] + ps[t + 128] + bo[col];
}

// K7: out = LayerNorm(x) * gamma + beta; grid B
__global__ __launch_bounds__(256) void k_ln(const float* __restrict__ x,
                                            const float* __restrict__ gamma,
                                            const float* __restrict__ beta,
                                            float* __restrict__ out) {
    int b = blockIdx.x;
    int t = threadIdx.x;
    __shared__ float red[8];
    float xv[4];
    float lsum = 0.f;
#pragma unroll
    for (int k = 0; k < 4; ++k) {
        xv[k] = x[b * DDIM + t + k * 256];
        lsum += xv[k];
    }
#pragma unroll
    for (int off = 32; off > 0; off >>= 1) lsum += __shfl_xor(lsum, off, 64);
    if ((t & 63) == 0) red[t >> 6] = lsum;
    __syncthreads();
    float mu = (red[0] + red[1] + red[2] + red[3]) * (1.f / DDIM);
    float lsq = 0.f;
#pragma unroll
    for (int k = 0; k < 4; ++k) {
        float dx = xv[k] - mu;
        lsq += dx * dx;
    }
#pragma unroll
    for (int off = 32; off > 0; off >>= 1) lsq += __shfl_xor(lsq, off, 64);
    if ((t & 63) == 0) red[4 + (t >> 6)] = lsq;
    __syncthreads();
    float var = (red[4] + red[5] + red[6] + red[7]) * (1.f / DDIM);
    float rstd = rsqrtf(var + LNEPS);
#pragma unroll
    for (int k = 0; k < 4; ++k) {
        int c = t + k * 256;
        out[b * DDIM + c] = (xv[k] - mu) * rstd * gamma[c] + beta[c];
    }
}

extern "C" void kernel_launch(void* const* d_in, const int* in_sizes, int n_in,
                              void* d_out, int out_size, void* d_ws, size_t ws_size,
                              hipStream_t stream) {
    const float* query = (const float*)d_in[0];
    const float* ctx   = (const float*)d_in[1];
    const float* dist  = (const float*)d_in[2];
    const int*   mask  = (const int*)d_in[3];
    const float* Wq = (const float*)d_in[4];
    const float* bq = (const float*)d_in[5];
    const float* Wk = (const float*)d_in[6];
    const float* bk = (const float*)d_in[7];
    const float* Wv = (const float*)d_in[8];
    const float* bv = (const float*)d_in[9];
    const float* Wo = (const float*)d_in[10];
    const float* bo = (const float*)d_in[11];
    const float* gamma = (const float*)d_in[12];
    const float* beta  = (const float*)d_in[13];
    float* out = (float*)d_out;

    int B = in_sizes[0] / DDIM;        // 32
    int N = in_sizes[1] / (B * DDIM);  // 4096

    float* ws = (float*)d_ws;
    float* q      = ws;                                   // B*D
    float* qp     = q + (size_t)B * DDIM;                 // B*H*D
    float* sb     = qp + (size_t)B * NH * DDIM;           // B*H
    float* partA  = sb + (size_t)B * NH;                  // B*NS*H*D
    float* partM  = partA + (size_t)B * NS * NH * DDIM;   // B*NS*H
    float* partL  = partM + (size_t)B * NS * NH;          // B*NS*H
    float* ctxa   = partL + (size_t)B * NS * NH;          // B*H*D
    float* oattn  = ctxa + (size_t)B * NH * DDIM;         // B*D
    float* xbuf   = oattn + (size_t)B * DDIM;             // B*D

    k_q<<<dim3(B, 8), 512, 0, stream>>>(query, Wq, bq, q);
    k_qp<<<dim3(B, DDIM / 16), 256, 0, stream>>>(q, Wk, qp);
    k_sb<<<1, B * NH, 0, stream>>>(q, bk, sb);
    k_flash<<<dim3(B, NS, 2), 256, 0, stream>>>(ctx, qp, sb, dist, mask,
                                                partA, partM, partL, N);
    k_comb<<<B * NH, 256, 0, stream>>>(partA, partM, partL, ctxa);
    k_vproj<<<dim3(B, 8), 256, 0, stream>>>(ctxa, Wv, bv, oattn);
    k_oproj<<<dim3(B, 8), 256, 0, stream>>>(query, oattn, Wo, bo, xbuf);
    k_ln<<<B, 256, 0, stream>>>(xbuf, gamma, beta, out);
}

// Round 7
// 381.658 us; speedup vs baseline: 1.3047x; 1.2867x over previous
//
#include <hip/hip_runtime.h>
#include <math.h>

#define DDIM 1024
#define NH 16
#define HDIM 64
#define SCALE 0.125f
#define DLAM -0.1f
#define LNEPS 1e-5f
#define PVSTR 68  // padded n-stride (bf16 elems) for transposed PV tile

typedef short bf16x8 __attribute__((ext_vector_type(8)));
typedef short bf16x4 __attribute__((ext_vector_type(4)));
typedef float f32x4 __attribute__((ext_vector_type(4)));

__device__ inline unsigned short f2bf(float x) {
    unsigned u = __builtin_bit_cast(unsigned, x);
    u += 0x7fffu + ((u >> 16) & 1u);
    return (unsigned short)(u >> 16);
}

__device__ inline bf16x8 pack8(float4 lo, float4 hi) {
    bf16x8 v;
    v[0] = (short)f2bf(lo.x); v[1] = (short)f2bf(lo.y);
    v[2] = (short)f2bf(lo.z); v[3] = (short)f2bf(lo.w);
    v[4] = (short)f2bf(hi.x); v[5] = (short)f2bf(hi.y);
    v[6] = (short)f2bf(hi.z); v[7] = (short)f2bf(hi.w);
    return v;
}

// K1: q[b,c] = query[b,:] @ Wq[:,c] + bq[c]; grid (B,8)
__global__ __launch_bounds__(512) void k_q(const float* __restrict__ query,
                                           const float* __restrict__ Wq,
                                           const float* __restrict__ bq,
                                           float* __restrict__ qout) {
    int b = blockIdx.x, c0 = blockIdx.y * 128;
    __shared__ float qs[DDIM];
    __shared__ float ps[512];
    int t = threadIdx.x;
    for (int i = t; i < DDIM; i += 512) qs[i] = query[b * DDIM + i];
    __syncthreads();
    int cl = t & 127;
    int col = c0 + cl;
    int d0 = (t >> 7) * 256;
    float acc = 0.f;
#pragma unroll 8
    for (int d = d0; d < d0 + 256; ++d)
        acc = fmaf(qs[d], Wq[(size_t)d * DDIM + col], acc);
    ps[t] = acc;
    __syncthreads();
    if (t < 128)
        qout[b * DDIM + col] = ps[t] + ps[t + 128] + ps[t + 256] + ps[t + 384] + bq[col];
}

// K2: qpb[b,h,d] = bf16( SCALE * sum_j Wk[d, h*64+j] * q[b, h*64+j] )
__global__ __launch_bounds__(256) void k_qp(const float* __restrict__ qin,
                                            const float* __restrict__ Wk,
                                            unsigned short* __restrict__ qpb) {
    int b = blockIdx.x, dt = blockIdx.y;
    __shared__ float qs[DDIM];
    for (int i = threadIdx.x; i < DDIM; i += 256) qs[i] = qin[b * DDIM + i];
    __syncthreads();
    int h = threadIdx.x & 15, dl = threadIdx.x >> 4;
    int d = dt * 16 + dl;
    const float* wr = Wk + (size_t)d * DDIM + h * HDIM;
    const float* qh = qs + h * HDIM;
    float acc = 0.f;
#pragma unroll
    for (int j = 0; j < HDIM; ++j) acc = fmaf(wr[j], qh[j], acc);
    qpb[((size_t)(b * NH + h)) * DDIM + d] = f2bf(acc * SCALE);
}

// K2b: sb[b,h] = SCALE * sum_j bk[h*64+j] * q[b, h*64+j]  (fp32)
__global__ __launch_bounds__(512) void k_sb(const float* __restrict__ qin,
                                            const float* __restrict__ bk,
                                            float* __restrict__ sb) {
    int idx = threadIdx.x;
    int b = idx >> 4, h = idx & 15;
    float acc = 0.f;
#pragma unroll
    for (int j = 0; j < HDIM; ++j)
        acc = fmaf(bk[h * HDIM + j], qin[b * DDIM + h * HDIM + j], acc);
    sb[idx] = acc * SCALE;
}

// K3: scores[b,h,n] = qp[b,h,:] . ctx[b,n,:]  via MFMA.
// grid (B, N/64), 256 thr = 4 waves, wave w owns n-subtile nb = y*64 + w*16.
// A-frag: qpb (bf16, global). B-frag: ctx fp32 global -> bf16 in-register.
__global__ __launch_bounds__(256) void k_scores(const float* __restrict__ ctx,
                                                const unsigned short* __restrict__ qpb,
                                                float* __restrict__ scores, int N) {
    int b = blockIdx.x;
    int t = threadIdx.x;
    int lane = t & 63, w = t >> 6;
    int nb = blockIdx.y * 64 + w * 16;
    int m = lane & 15, g = lane >> 4;
    const unsigned short* qrow = qpb + ((size_t)(b * NH + m)) * DDIM + g * 8;
    const float* crow = ctx + ((size_t)b * N + nb + m) * DDIM + g * 8;
    f32x4 c = {0.f, 0.f, 0.f, 0.f};
#pragma unroll 4
    for (int kk = 0; kk < 32; ++kk) {
        bf16x8 a = *(const bf16x8*)(qrow + kk * 32);
        float4 f0 = *(const float4*)(crow + kk * 32);
        float4 f1 = *(const float4*)(crow + kk * 32 + 4);
        bf16x8 bb = pack8(f0, f1);
        c = __builtin_amdgcn_mfma_f32_16x16x32_bf16(a, bb, c, 0, 0, 0);
    }
#pragma unroll
    for (int r = 0; r < 4; ++r)
        scores[((size_t)(b * NH + g * 4 + r)) * N + nb + m] = c[r];
}

// K4: softmax over full row N with sb + dist*lambda + mask; writes NORMALIZED P (bf16).
__global__ __launch_bounds__(256) void k_softmax(const float* __restrict__ scores,
                                                 const float* __restrict__ sb,
                                                 const float* __restrict__ dist,
                                                 const int* __restrict__ mask,
                                                 unsigned short* __restrict__ P, int N) {
    int row = blockIdx.x;  // b*16 + h
    int b = row >> 4;
    const float* s = scores + (size_t)row * N;
    float sbv = sb[row];
    int t = threadIdx.x;
    __shared__ float red[4];
    float v[16];
    float mx = -3.4e38f;
#pragma unroll
    for (int i = 0; i < 16; ++i) {
        int n = t + i * 256;
        float x = s[n] + sbv + dist[(size_t)b * N + n] * DLAM;
        if (mask[(size_t)b * N + n] == 0) x = -1e30f;
        v[i] = x;
        mx = fmaxf(mx, x);
    }
#pragma unroll
    for (int off = 32; off > 0; off >>= 1) mx = fmaxf(mx, __shfl_xor(mx, off, 64));
    if ((t & 63) == 0) red[t >> 6] = mx;
    __syncthreads();
    mx = fmaxf(fmaxf(red[0], red[1]), fmaxf(red[2], red[3]));
    __syncthreads();
    float sum = 0.f;
#pragma unroll
    for (int i = 0; i < 16; ++i) {
        v[i] = __expf(v[i] - mx);
        sum += v[i];
    }
#pragma unroll
    for (int off = 32; off > 0; off >>= 1) sum += __shfl_xor(sum, off, 64);
    if ((t & 63) == 0) red[t >> 6] = sum;
    __syncthreads();
    sum = red[0] + red[1] + red[2] + red[3];
    float inv = 1.f / sum;
#pragma unroll
    for (int i = 0; i < 16; ++i)
        P[(size_t)row * N + t + i * 256] = f2bf(v[i] * inv);
}

// K5: ctxa[b,h,d] = sum_n P[b,h,n] * ctx[b,n,d]  via MFMA.
// grid (B, 8): block owns 128-d slice; 4 waves x 32-d each (2 subtiles).
// ctx staged per 64-n slice into transposed bf16 LDS [128 d][PVSTR n], double-buffered.
__global__ __launch_bounds__(256) void k_pv(const float* __restrict__ ctx,
                                            const unsigned short* __restrict__ P,
                                            float* __restrict__ ctxa, int N) {
    int b = blockIdx.x;
    int dbase = blockIdx.y * 128;
    __shared__ unsigned short T[2][128 * PVSTR];
    int t = threadIdx.x;
    int lane = t & 63, w = t >> 6;
    int m = lane & 15, g = lane >> 4;
    int rp = t & 31;        // row-pair index (rows 2rp, 2rp+1 of the 64-n slice)
    int ds0 = t >> 5;       // 0..7 -> d-segments ds0 and ds0+8
    const float* cbase = ctx + ((size_t)b * N) * DDIM + dbase;
    f32x4 acc0 = {0.f, 0.f, 0.f, 0.f}, acc1 = {0.f, 0.f, 0.f, 0.f};
    int dw = w * 32;

    auto STAGE = [&](int it, int buf) {
        const float* src = cbase + ((size_t)it * 64) * DDIM;
#pragma unroll
        for (int k = 0; k < 2; ++k) {
            int dseg = (ds0 + 8 * k) * 8;  // 0..120 step 8
            const float* r0 = src + (size_t)(2 * rp) * DDIM + dseg;
            const float* r1 = r0 + DDIM;
            float4 a0 = *(const float4*)(r0);
            float4 a1 = *(const float4*)(r0 + 4);
            float4 b0 = *(const float4*)(r1);
            float4 b1 = *(const float4*)(r1 + 4);
            float va[8] = {a0.x, a0.y, a0.z, a0.w, a1.x, a1.y, a1.z, a1.w};
            float vb[8] = {b0.x, b0.y, b0.z, b0.w, b1.x, b1.y, b1.z, b1.w};
            unsigned short* dst = &T[buf][0];
#pragma unroll
            for (int dd = 0; dd < 8; ++dd) {
                unsigned pk = (unsigned)f2bf(va[dd]) | ((unsigned)f2bf(vb[dd]) << 16);
                *(unsigned*)(dst + (dseg + dd) * PVSTR + 2 * rp) = pk;
            }
        }
    };

    STAGE(0, 0);
    __syncthreads();
    int NIT = N / 64;
    for (int it = 0; it < NIT; ++it) {
        if (it + 1 < NIT) STAGE(it + 1, (it + 1) & 1);
        int buf = it & 1;
        const unsigned short* Prow = P + ((size_t)(b * NH + m)) * N + it * 64 + g * 8;
#pragma unroll
        for (int kk = 0; kk < 2; ++kk) {
            bf16x8 a = *(const bf16x8*)(Prow + kk * 32);
            int n0 = kk * 32 + g * 8;
#pragma unroll
            for (int ds = 0; ds < 2; ++ds) {
                int d = dw + ds * 16 + m;
                const unsigned short* tp = &T[buf][d * PVSTR + n0];
                bf16x4 lo = *(const bf16x4*)(tp);
                bf16x4 hi = *(const bf16x4*)(tp + 4);
                bf16x8 bb;
                bb[0] = lo[0]; bb[1] = lo[1]; bb[2] = lo[2]; bb[3] = lo[3];
                bb[4] = hi[0]; bb[5] = hi[1]; bb[6] = hi[2]; bb[7] = hi[3];
                if (ds == 0)
                    acc0 = __builtin_amdgcn_mfma_f32_16x16x32_bf16(a, bb, acc0, 0, 0, 0);
                else
                    acc1 = __builtin_amdgcn_mfma_f32_16x16x32_bf16(a, bb, acc1, 0, 0, 0);
            }
        }
        __syncthreads();
    }
#pragma unroll
    for (int r = 0; r < 4; ++r) {
        int h = g * 4 + r;
        ctxa[((size_t)(b * NH + h)) * DDIM + dbase + dw + m] = acc0[r];
        ctxa[((size_t)(b * NH + h)) * DDIM + dbase + dw + 16 + m] = acc1[r];
    }
}

// K6: oattn[b,c] = ctxa[b, c>>6, :] . Wv[:, c] + bv[c]; grid (B, 8)
__global__ __launch_bounds__(256) void k_vproj(const float* __restrict__ ctxa,
                                               const float* __restrict__ Wv,
                                               const float* __restrict__ bv,
                                               float* __restrict__ oattn) {
    int b = blockIdx.x, c0 = blockIdx.y * 128;
    int h0 = c0 >> 6;
    __shared__ float cs[2][DDIM];
    __shared__ float ps[256];
    for (int i = threadIdx.x; i < 2 * DDIM; i += 256)
        cs[i >> 10][i & 1023] =
            ctxa[((size_t)(b * NH + h0 + (i >> 10))) * DDIM + (i & 1023)];
    __syncthreads();
    int t = threadIdx.x;
    int cl = t & 127;
    int col = c0 + cl;
    int hl = cl >> 6;
    int d0 = (t >> 7) * 512;
    float acc = 0.f;
#pragma unroll 8
    for (int d = d0; d < d0 + 512; ++d)
        acc = fmaf(cs[hl][d], Wv[(size_t)d * DDIM + col], acc);
    ps[t] = acc;
    __syncthreads();
    if (t < 128) oattn[b * DDIM + col] = ps[t] + ps[t + 128] + bv[col];
}

// K7: x[b,c] = query[b,c] + oattn[b,:] . Wo[:,c] + bo[c]; grid (B, 8)
__global__ __launch_bounds__(256) void k_oproj(const float* __restrict__ query,
                                               const float* __restrict__ oattn,
                                               const float* __restrict__ Wo,
                                               const float* __restrict__ bo,
                                               float* __restrict__ x) {
    int b = blockIdx.x, c0 = blockIdx.y * 128;
    __shared__ float os[DDIM];
    __shared__ float ps[256];
    for (int i = threadIdx.x; i < DDIM; i += 256) os[i] = oattn[b * DDIM + i];
    __syncthreads();
    int t = threadIdx.x;
    int col = c0 + (t & 127);
    int d0 = (t >> 7) * 512;
    float acc = 0.f;
#pragma unroll 8
    for (int d = d0; d < d0 + 512; ++d)
        acc = fmaf(os[d], Wo[(size_t)d * DDIM + col], acc);
    ps[t] = acc;
    __syncthreads();
    if (t < 128)
        x[b * DDIM + col] = query[b * DDIM + col] + ps[t] + ps[t + 128] + bo[col];
}

// K8: out = LayerNorm(x) * gamma + beta; grid B
__global__ __launch_bounds__(256) void k_ln(const float* __restrict__ x,
                                            const float* __restrict__ gamma,
                                            const float* __restrict__ beta,
                                            float* __restrict__ out) {
    int b = blockIdx.x;
    int t = threadIdx.x;
    __shared__ float red[8];
    float xv[4];
    float lsum = 0.f;
#pragma unroll
    for (int k = 0; k < 4; ++k) {
        xv[k] = x[b * DDIM + t + k * 256];
        lsum += xv[k];
    }
#pragma unroll
    for (int off = 32; off > 0; off >>= 1) lsum += __shfl_xor(lsum, off, 64);
    if ((t & 63) == 0) red[t >> 6] = lsum;
    __syncthreads();
    float mu = (red[0] + red[1] + red[2] + red[3]) * (1.f / DDIM);
    float lsq = 0.f;
#pragma unroll
    for (int k = 0; k < 4; ++k) {
        float dx = xv[k] - mu;
        lsq += dx * dx;
    }
#pragma unroll
    for (int off = 32; off > 0; off >>= 1) lsq += __shfl_xor(lsq, off, 64);
    if ((t & 63) == 0) red[4 + (t >> 6)] = lsq;
    __syncthreads();
    float var = (red[4] + red[5] + red[6] + red[7]) * (1.f / DDIM);
    float rstd = rsqrtf(var + LNEPS);
#pragma unroll
    for (int k = 0; k < 4; ++k) {
        int c = t + k * 256;
        out[b * DDIM + c] = (xv[k] - mu) * rstd * gamma[c] + beta[c];
    }
}

extern "C" void kernel_launch(void* const* d_in, const int* in_sizes, int n_in,
                              void* d_out, int out_size, void* d_ws, size_t ws_size,
                              hipStream_t stream) {
    const float* query = (const float*)d_in[0];
    const float* ctx   = (const float*)d_in[1];
    const float* dist  = (const float*)d_in[2];
    const int*   mask  = (const int*)d_in[3];
    const float* Wq = (const float*)d_in[4];
    const float* bq = (const float*)d_in[5];
    const float* Wk = (const float*)d_in[6];
    const float* bk = (const float*)d_in[7];
    const float* Wv = (const float*)d_in[8];
    const float* bv = (const float*)d_in[9];
    const float* Wo = (const float*)d_in[10];
    const float* bo = (const float*)d_in[11];
    const float* gamma = (const float*)d_in[12];
    const float* beta  = (const float*)d_in[13];
    float* out = (float*)d_out;

    int B = in_sizes[0] / DDIM;        // 32
    int N = in_sizes[1] / (B * DDIM);  // 4096

    float* ws = (float*)d_ws;
    float* q = ws;                                         // B*D
    unsigned short* qpb = (unsigned short*)(q + (size_t)B * DDIM);      // B*NH*D bf16
    float* sb = (float*)(qpb + (size_t)B * NH * DDIM);                  // B*NH
    float* scores = sb + (size_t)B * NH;                                // B*NH*N
    unsigned short* P = (unsigned short*)(scores + (size_t)B * NH * N); // B*NH*N bf16
    float* ctxa = (float*)(P + (size_t)B * NH * N);                     // B*NH*D
    float* oattn = ctxa + (size_t)B * NH * DDIM;                        // B*D
    float* xbuf = oattn + (size_t)B * DDIM;                             // B*D

    k_q<<<dim3(B, 8), 512, 0, stream>>>(query, Wq, bq, q);
    k_qp<<<dim3(B, DDIM / 16), 256, 0, stream>>>(q, Wk, qpb);
    k_sb<<<1, B * NH, 0, stream>>>(q, bk, sb);
    k_scores<<<dim3(B, N / 64), 256, 0, stream>>>(ctx, qpb, scores, N);
    k_softmax<<<B * NH, 256, 0, stream>>>(scores, sb, dist, mask, P, N);
    k_pv<<<dim3(B, 8), 256, 0, stream>>>(ctx, P, ctxa, N);
    k_vproj<<<dim3(B, 8), 256, 0, stream>>>(ctxa, Wv, bv, oattn);
    k_oproj<<<dim3(B, 8), 256, 0, stream>>>(query, oattn, Wo, bo, xbuf);
    k_ln<<<B, 256, 0, stream>>>(xbuf, gamma, beta, out);
}

// Round 8
// 348.450 us; speedup vs baseline: 1.4290x; 1.0953x over previous
//
#include <hip/hip_runtime.h>
#include <hip/hip_bf16.h>
#include <math.h>

#define DDIM 1024
#define NH 16
#define HDIM 64
#define SCALE 0.125f
#define DLAM -0.1f
#define LNEPS 1e-5f
#define PVSTR 68  // padded n-stride (bf16 elems) for transposed PV tile
#define NSP 4     // n-splits for k_pv

typedef short bf16x8 __attribute__((ext_vector_type(8)));
typedef short bf16x4 __attribute__((ext_vector_type(4)));
typedef float f32x4 __attribute__((ext_vector_type(4)));

__device__ inline unsigned short f2bf(float x) {
    return __builtin_bit_cast(unsigned short, __float2bfloat16(x));
}

__device__ inline bf16x8 pack8(float4 lo, float4 hi) {
    bf16x8 v;
    v[0] = (short)f2bf(lo.x); v[1] = (short)f2bf(lo.y);
    v[2] = (short)f2bf(lo.z); v[3] = (short)f2bf(lo.w);
    v[4] = (short)f2bf(hi.x); v[5] = (short)f2bf(hi.y);
    v[6] = (short)f2bf(hi.z); v[7] = (short)f2bf(hi.w);
    return v;
}

// K1: q[b,c] = query[b,:] @ Wq[:,c] + bq[c]; grid (B,8)
__global__ __launch_bounds__(512) void k_q(const float* __restrict__ query,
                                           const float* __restrict__ Wq,
                                           const float* __restrict__ bq,
                                           float* __restrict__ qout) {
    int b = blockIdx.x, c0 = blockIdx.y * 128;
    __shared__ float qs[DDIM];
    __shared__ float ps[512];
    int t = threadIdx.x;
    for (int i = t; i < DDIM; i += 512) qs[i] = query[b * DDIM + i];
    __syncthreads();
    int cl = t & 127;
    int col = c0 + cl;
    int d0 = (t >> 7) * 256;
    float acc = 0.f;
#pragma unroll 8
    for (int d = d0; d < d0 + 256; ++d)
        acc = fmaf(qs[d], Wq[(size_t)d * DDIM + col], acc);
    ps[t] = acc;
    __syncthreads();
    if (t < 128)
        qout[b * DDIM + col] = ps[t] + ps[t + 128] + ps[t + 256] + ps[t + 384] + bq[col];
}

// K2: qpb[b,h,d] = bf16( SCALE * sum_j Wk[d, h*64+j] * q[b, h*64+j] )
__global__ __launch_bounds__(256) void k_qp(const float* __restrict__ qin,
                                            const float* __restrict__ Wk,
                                            unsigned short* __restrict__ qpb) {
    int b = blockIdx.x, dt = blockIdx.y;
    __shared__ float qs[DDIM];
    for (int i = threadIdx.x; i < DDIM; i += 256) qs[i] = qin[b * DDIM + i];
    __syncthreads();
    int h = threadIdx.x & 15, dl = threadIdx.x >> 4;
    int d = dt * 16 + dl;
    const float* wr = Wk + (size_t)d * DDIM + h * HDIM;
    const float* qh = qs + h * HDIM;
    float acc = 0.f;
#pragma unroll
    for (int j = 0; j < HDIM; ++j) acc = fmaf(wr[j], qh[j], acc);
    qpb[((size_t)(b * NH + h)) * DDIM + d] = f2bf(acc * SCALE);
}

// K2b: sb[b,h] = SCALE * sum_j bk[h*64+j] * q[b, h*64+j]  (fp32)
__global__ __launch_bounds__(512) void k_sb(const float* __restrict__ qin,
                                            const float* __restrict__ bk,
                                            float* __restrict__ sb) {
    int idx = threadIdx.x;
    int b = idx >> 4, h = idx & 15;
    float acc = 0.f;
#pragma unroll
    for (int j = 0; j < HDIM; ++j)
        acc = fmaf(bk[h * HDIM + j], qin[b * DDIM + h * HDIM + j], acc);
    sb[idx] = acc * SCALE;
}

// K3: scores[b,h,n] = qp[b,h,:] . ctx[b,n,:]  via MFMA.
// grid (B, N/128), 4 waves; each wave owns 2 n-subtiles sharing the A-frag.
__global__ __launch_bounds__(256) void k_scores(const float* __restrict__ ctx,
                                                const unsigned short* __restrict__ qpb,
                                                float* __restrict__ scores, int N) {
    int b = blockIdx.x;
    int t = threadIdx.x;
    int lane = t & 63, w = t >> 6;
    int nb = blockIdx.y * 128 + w * 32;
    int m = lane & 15, g = lane >> 4;
    const unsigned short* qrow = qpb + ((size_t)(b * NH + m)) * DDIM + g * 8;
    const float* crow0 = ctx + ((size_t)b * N + nb + m) * DDIM + g * 8;
    const float* crow1 = crow0 + (size_t)16 * DDIM;
    f32x4 c0 = {0.f, 0.f, 0.f, 0.f}, c1 = {0.f, 0.f, 0.f, 0.f};
#pragma unroll 4
    for (int kk = 0; kk < 32; ++kk) {
        bf16x8 a = *(const bf16x8*)(qrow + kk * 32);
        float4 f00 = *(const float4*)(crow0 + kk * 32);
        float4 f01 = *(const float4*)(crow0 + kk * 32 + 4);
        float4 f10 = *(const float4*)(crow1 + kk * 32);
        float4 f11 = *(const float4*)(crow1 + kk * 32 + 4);
        c0 = __builtin_amdgcn_mfma_f32_16x16x32_bf16(a, pack8(f00, f01), c0, 0, 0, 0);
        c1 = __builtin_amdgcn_mfma_f32_16x16x32_bf16(a, pack8(f10, f11), c1, 0, 0, 0);
    }
#pragma unroll
    for (int r = 0; r < 4; ++r) {
        scores[((size_t)(b * NH + g * 4 + r)) * N + nb + m] = c0[r];
        scores[((size_t)(b * NH + g * 4 + r)) * N + nb + 16 + m] = c1[r];
    }
}

// K4: softmax over full row N with sb + dist*lambda + mask; writes NORMALIZED P (bf16).
__global__ __launch_bounds__(256) void k_softmax(const float* __restrict__ scores,
                                                 const float* __restrict__ sb,
                                                 const float* __restrict__ dist,
                                                 const int* __restrict__ mask,
                                                 unsigned short* __restrict__ P, int N) {
    int row = blockIdx.x;  // b*16 + h
    int b = row >> 4;
    const float* s = scores + (size_t)row * N;
    float sbv = sb[row];
    int t = threadIdx.x;
    __shared__ float red[4];
    float v[16];
    float mx = -3.4e38f;
#pragma unroll
    for (int i = 0; i < 16; ++i) {
        int n = t + i * 256;
        float x = s[n] + sbv + dist[(size_t)b * N + n] * DLAM;
        if (mask[(size_t)b * N + n] == 0) x = -1e30f;
        v[i] = x;
        mx = fmaxf(mx, x);
    }
#pragma unroll
    for (int off = 32; off > 0; off >>= 1) mx = fmaxf(mx, __shfl_xor(mx, off, 64));
    if ((t & 63) == 0) red[t >> 6] = mx;
    __syncthreads();
    mx = fmaxf(fmaxf(red[0], red[1]), fmaxf(red[2], red[3]));
    __syncthreads();
    float sum = 0.f;
#pragma unroll
    for (int i = 0; i < 16; ++i) {
        v[i] = __expf(v[i] - mx);
        sum += v[i];
    }
#pragma unroll
    for (int off = 32; off > 0; off >>= 1) sum += __shfl_xor(sum, off, 64);
    if ((t & 63) == 0) red[t >> 6] = sum;
    __syncthreads();
    sum = red[0] + red[1] + red[2] + red[3];
    float inv = 1.f / sum;
#pragma unroll
    for (int i = 0; i < 16; ++i)
        P[(size_t)row * N + t + i * 256] = f2bf(v[i] * inv);
}

// K5: partO[(b*NSP+nsp)][h][dbase..] = sum_{n in split} P[b,h,n] * ctx[b,n,d]  via MFMA.
// grid (B, 8, NSP): block owns 128-d slice x N/NSP rows; 4 waves x 32-d each.
// ctx staged per 64-n slice into transposed bf16 LDS [128 d][PVSTR n], double-buffered.
__global__ __launch_bounds__(256) void k_pv(const float* __restrict__ ctx,
                                            const unsigned short* __restrict__ P,
                                            float* __restrict__ partO, int N) {
    int b = blockIdx.x;
    int dbase = blockIdx.y * 128;
    int nsp = blockIdx.z;
    __shared__ unsigned short T[2][128 * PVSTR];
    int t = threadIdx.x;
    int lane = t & 63, w = t >> 6;
    int m = lane & 15, g = lane >> 4;
    int rp = t & 31;        // row-pair index (rows 2rp, 2rp+1 of the 64-n slice)
    int ds0 = t >> 5;       // 0..7 -> d-segments ds0 and ds0+8
    int NIT = N / (NSP * 64);
    int nb0 = nsp * NIT * 64;
    const float* cbase = ctx + ((size_t)b * N) * DDIM + dbase;
    f32x4 acc0 = {0.f, 0.f, 0.f, 0.f}, acc1 = {0.f, 0.f, 0.f, 0.f};
    int dw = w * 32;

    auto STAGE = [&](int it, int buf) {
        const float* src = cbase + ((size_t)(nb0 + it * 64)) * DDIM;
#pragma unroll
        for (int k = 0; k < 2; ++k) {
            int dseg = (ds0 + 8 * k) * 8;  // 0..120 step 8
            const float* r0 = src + (size_t)(2 * rp) * DDIM + dseg;
            const float* r1 = r0 + DDIM;
            float4 a0 = *(const float4*)(r0);
            float4 a1 = *(const float4*)(r0 + 4);
            float4 b0 = *(const float4*)(r1);
            float4 b1 = *(const float4*)(r1 + 4);
            float va[8] = {a0.x, a0.y, a0.z, a0.w, a1.x, a1.y, a1.z, a1.w};
            float vb[8] = {b0.x, b0.y, b0.z, b0.w, b1.x, b1.y, b1.z, b1.w};
            unsigned short* dst = &T[buf][0];
#pragma unroll
            for (int dd = 0; dd < 8; ++dd) {
                unsigned pk = (unsigned)f2bf(va[dd]) | ((unsigned)f2bf(vb[dd]) << 16);
                *(unsigned*)(dst + (dseg + dd) * PVSTR + 2 * rp) = pk;
            }
        }
    };

    STAGE(0, 0);
    __syncthreads();
    for (int it = 0; it < NIT; ++it) {
        if (it + 1 < NIT) STAGE(it + 1, (it + 1) & 1);
        int buf = it & 1;
        const unsigned short* Prow =
            P + ((size_t)(b * NH + m)) * N + nb0 + it * 64 + g * 8;
#pragma unroll
        for (int kk = 0; kk < 2; ++kk) {
            bf16x8 a = *(const bf16x8*)(Prow + kk * 32);
            int n0 = kk * 32 + g * 8;
#pragma unroll
            for (int ds = 0; ds < 2; ++ds) {
                int d = dw + ds * 16 + m;
                const unsigned short* tp = &T[buf][d * PVSTR + n0];
                bf16x4 lo = *(const bf16x4*)(tp);
                bf16x4 hi = *(const bf16x4*)(tp + 4);
                bf16x8 bb;
                bb[0] = lo[0]; bb[1] = lo[1]; bb[2] = lo[2]; bb[3] = lo[3];
                bb[4] = hi[0]; bb[5] = hi[1]; bb[6] = hi[2]; bb[7] = hi[3];
                if (ds == 0)
                    acc0 = __builtin_amdgcn_mfma_f32_16x16x32_bf16(a, bb, acc0, 0, 0, 0);
                else
                    acc1 = __builtin_amdgcn_mfma_f32_16x16x32_bf16(a, bb, acc1, 0, 0, 0);
            }
        }
        __syncthreads();
    }
#pragma unroll
    for (int r = 0; r < 4; ++r) {
        int h = g * 4 + r;
        float* dst = partO + ((size_t)((b * NSP + nsp) * NH + h)) * DDIM + dbase + dw;
        dst[m] = acc0[r];
        dst[16 + m] = acc1[r];
    }
}

// K5b: ctxa[b,h,d] = sum_nsp partO
__global__ __launch_bounds__(256) void k_pvred(const float* __restrict__ partO,
                                               float* __restrict__ ctxa) {
    int row = blockIdx.x;  // b*NH + h
    int b = row >> 4, h = row & 15;
    int t = threadIdx.x;
#pragma unroll
    for (int k = 0; k < 4; ++k) {
        int d = t + k * 256;
        float s = 0.f;
#pragma unroll
        for (int nsp = 0; nsp < NSP; ++nsp)
            s += partO[((size_t)((b * NSP + nsp) * NH + h)) * DDIM + d];
        ctxa[(size_t)row * DDIM + d] = s;
    }
}

// K6: oattn[b,c] = ctxa[b, c>>6, :] . Wv[:, c] + bv[c]; grid (B, 8)
__global__ __launch_bounds__(256) void k_vproj(const float* __restrict__ ctxa,
                                               const float* __restrict__ Wv,
                                               const float* __restrict__ bv,
                                               float* __restrict__ oattn) {
    int b = blockIdx.x, c0 = blockIdx.y * 128;
    int h0 = c0 >> 6;
    __shared__ float cs[2][DDIM];
    __shared__ float ps[256];
    for (int i = threadIdx.x; i < 2 * DDIM; i += 256)
        cs[i >> 10][i & 1023] =
            ctxa[((size_t)(b * NH + h0 + (i >> 10))) * DDIM + (i & 1023)];
    __syncthreads();
    int t = threadIdx.x;
    int cl = t & 127;
    int col = c0 + cl;
    int hl = cl >> 6;
    int d0 = (t >> 7) * 512;
    float acc = 0.f;
#pragma unroll 8
    for (int d = d0; d < d0 + 512; ++d)
        acc = fmaf(cs[hl][d], Wv[(size_t)d * DDIM + col], acc);
    ps[t] = acc;
    __syncthreads();
    if (t < 128) oattn[b * DDIM + col] = ps[t] + ps[t + 128] + bv[col];
}

// K7: x[b,c] = query[b,c] + oattn[b,:] . Wo[:,c] + bo[c]; grid (B, 8)
__global__ __launch_bounds__(256) void k_oproj(const float* __restrict__ query,
                                               const float* __restrict__ oattn,
                                               const float* __restrict__ Wo,
                                               const float* __restrict__ bo,
                                               float* __restrict__ x) {
    int b = blockIdx.x, c0 = blockIdx.y * 128;
    __shared__ float os[DDIM];
    __shared__ float ps[256];
    for (int i = threadIdx.x; i < DDIM; i += 256) os[i] = oattn[b * DDIM + i];
    __syncthreads();
    int t = threadIdx.x;
    int col = c0 + (t & 127);
    int d0 = (t >> 7) * 512;
    float acc = 0.f;
#pragma unroll 8
    for (int d = d0; d < d0 + 512; ++d)
        acc = fmaf(os[d], Wo[(size_t)d * DDIM + col], acc);
    ps[t] = acc;
    __syncthreads();
    if (t < 128)
        x[b * DDIM + col] = query[b * DDIM + col] + ps[t] + ps[t + 128] + bo[col];
}

// K8: out = LayerNorm(x) * gamma + beta; grid B
__global__ __launch_bounds__(256) void k_ln(const float* __restrict__ x,
                                            const float* __restrict__ gamma,
                                            const float* __restrict__ beta,
                                            float* __restrict__ out) {
    int b = blockIdx.x;
    int t = threadIdx.x;
    __shared__ float red[8];
    float xv[4];
    float lsum = 0.f;
#pragma unroll
    for (int k = 0; k < 4; ++k) {
        xv[k] = x[b * DDIM + t + k * 256];
        lsum += xv[k];
    }
#pragma unroll
    for (int off = 32; off > 0; off >>= 1) lsum += __shfl_xor(lsum, off, 64);
    if ((t & 63) == 0) red[t >> 6] = lsum;
    __syncthreads();
    float mu = (red[0] + red[1] + red[2] + red[3]) * (1.f / DDIM);
    float lsq = 0.f;
#pragma unroll
    for (int k = 0; k < 4; ++k) {
        float dx = xv[k] - mu;
        lsq += dx * dx;
    }
#pragma unroll
    for (int off = 32; off > 0; off >>= 1) lsq += __shfl_xor(lsq, off, 64);
    if ((t & 63) == 0) red[4 + (t >> 6)] = lsq;
    __syncthreads();
    float var = (red[4] + red[5] + red[6] + red[7]) * (1.f / DDIM);
    float rstd = rsqrtf(var + LNEPS);
#pragma unroll
    for (int k = 0; k < 4; ++k) {
        int c = t + k * 256;
        out[b * DDIM + c] = (xv[k] - mu) * rstd * gamma[c] + beta[c];
    }
}

extern "C" void kernel_launch(void* const* d_in, const int* in_sizes, int n_in,
                              void* d_out, int out_size, void* d_ws, size_t ws_size,
                              hipStream_t stream) {
    const float* query = (const float*)d_in[0];
    const float* ctx   = (const float*)d_in[1];
    const float* dist  = (const float*)d_in[2];
    const int*   mask  = (const int*)d_in[3];
    const float* Wq = (const float*)d_in[4];
    const float* bq = (const float*)d_in[5];
    const float* Wk = (const float*)d_in[6];
    const float* bk = (const float*)d_in[7];
    const float* Wv = (const float*)d_in[8];
    const float* bv = (const float*)d_in[9];
    const float* Wo = (const float*)d_in[10];
    const float* bo = (const float*)d_in[11];
    const float* gamma = (const float*)d_in[12];
    const float* beta  = (const float*)d_in[13];
    float* out = (float*)d_out;

    int B = in_sizes[0] / DDIM;        // 32
    int N = in_sizes[1] / (B * DDIM);  // 4096

    float* ws = (float*)d_ws;
    float* q = ws;                                         // B*D
    unsigned short* qpb = (unsigned short*)(q + (size_t)B * DDIM);      // B*NH*D bf16
    float* sb = (float*)(qpb + (size_t)B * NH * DDIM);                  // B*NH
    float* scores = sb + (size_t)B * NH;                                // B*NH*N
    unsigned short* P = (unsigned short*)(scores + (size_t)B * NH * N); // B*NH*N bf16
    float* partO = (float*)(P + (size_t)B * NH * N);                    // B*NSP*NH*D
    float* ctxa = partO + (size_t)B * NSP * NH * DDIM;                  // B*NH*D
    float* oattn = ctxa + (size_t)B * NH * DDIM;                        // B*D
    float* xbuf = oattn + (size_t)B * DDIM;                             // B*D

    k_q<<<dim3(B, 8), 512, 0, stream>>>(query, Wq, bq, q);
    k_qp<<<dim3(B, DDIM / 16), 256, 0, stream>>>(q, Wk, qpb);
    k_sb<<<1, B * NH, 0, stream>>>(q, bk, sb);
    k_scores<<<dim3(B, N / 128), 256, 0, stream>>>(ctx, qpb, scores, N);
    k_softmax<<<B * NH, 256, 0, stream>>>(scores, sb, dist, mask, P, N);
    k_pv<<<dim3(B, 8, NSP), 256, 0, stream>>>(ctx, P, partO, N);
    k_pvred<<<B * NH, 256, 0, stream>>>(partO, ctxa);
    k_vproj<<<dim3(B, 8), 256, 0, stream>>>(ctxa, Wv, bv, oattn);
    k_oproj<<<dim3(B, 8), 256, 0, stream>>>(query, oattn, Wo, bo, xbuf);
    k_ln<<<B, 256, 0, stream>>>(xbuf, gamma, beta, out);
}

// Round 9
// 244.661 us; speedup vs baseline: 2.0352x; 1.4242x over previous
//
#include <hip/hip_runtime.h>
#include <hip/hip_bf16.h>
#include <math.h>

#define DDIM 1024
#define NH 16
#define HDIM 64
#define SCALE 0.125f
#define DLAM -0.1f
#define LNEPS 1e-5f
#define NS 16      // n-splits (blocks per batch) for k_flash2
#define CHW 16     // chunk height (rows per chunk)
#define BROW 256   // rows per block = N/NS
#define CBSTR 1032 // padded LDS row stride (bf16 elems): 2064B = 129*16 -> 16B-aligned, 2-way banks

typedef short bf16x8 __attribute__((ext_vector_type(8)));
typedef float f32x4 __attribute__((ext_vector_type(4)));

__device__ inline unsigned short f2bf(float x) {
    return __builtin_bit_cast(unsigned short, __float2bfloat16(x));
}
__device__ inline float bfhi2f(unsigned u) {  // upper 16 bits as bf16
    return __builtin_bit_cast(float, u & 0xffff0000u);
}
__device__ inline float bflo2f(unsigned u) {  // lower 16 bits as bf16
    return __builtin_bit_cast(float, u << 16);
}

// K1: q[b,c] = query[b,:] @ Wq[:,c] + bq[c]; grid (B,8)
__global__ __launch_bounds__(512) void k_q(const float* __restrict__ query,
                                           const float* __restrict__ Wq,
                                           const float* __restrict__ bq,
                                           float* __restrict__ qout) {
    int b = blockIdx.x, c0 = blockIdx.y * 128;
    __shared__ float qs[DDIM];
    __shared__ float ps[512];
    int t = threadIdx.x;
    for (int i = t; i < DDIM; i += 512) qs[i] = query[b * DDIM + i];
    __syncthreads();
    int cl = t & 127;
    int col = c0 + cl;
    int d0 = (t >> 7) * 256;
    float acc = 0.f;
#pragma unroll 8
    for (int d = d0; d < d0 + 256; ++d)
        acc = fmaf(qs[d], Wq[(size_t)d * DDIM + col], acc);
    ps[t] = acc;
    __syncthreads();
    if (t < 128)
        qout[b * DDIM + col] = ps[t] + ps[t + 128] + ps[t + 256] + ps[t + 384] + bq[col];
}

// K2: qpb[b,h,d] = bf16( SCALE * sum_j Wk[d, h*64+j] * q[b, h*64+j] )
__global__ __launch_bounds__(256) void k_qp(const float* __restrict__ qin,
                                            const float* __restrict__ Wk,
                                            unsigned short* __restrict__ qpb) {
    int b = blockIdx.x, dt = blockIdx.y;
    __shared__ float qs[DDIM];
    for (int i = threadIdx.x; i < DDIM; i += 256) qs[i] = qin[b * DDIM + i];
    __syncthreads();
    int h = threadIdx.x & 15, dl = threadIdx.x >> 4;
    int d = dt * 16 + dl;
    const float* wr = Wk + (size_t)d * DDIM + h * HDIM;
    const float* qh = qs + h * HDIM;
    float acc = 0.f;
#pragma unroll
    for (int j = 0; j < HDIM; ++j) acc = fmaf(wr[j], qh[j], acc);
    qpb[((size_t)(b * NH + h)) * DDIM + d] = f2bf(acc * SCALE);
}

// K2b: sb[b,h] = SCALE * sum_j bk[h*64+j] * q[b, h*64+j]
__global__ __launch_bounds__(512) void k_sb(const float* __restrict__ qin,
                                            const float* __restrict__ bk,
                                            float* __restrict__ sb) {
    int idx = threadIdx.x;
    int b = idx >> 4, h = idx & 15;
    float acc = 0.f;
#pragma unroll
    for (int j = 0; j < HDIM; ++j)
        acc = fmaf(bk[h * HDIM + j], qin[b * DDIM + h * HDIM + j], acc);
    sb[idx] = acc * SCALE;
}

// K3 (fused): per block (b, ns): rows [ns*256, ns*256+256), chunks of 16.
// ctx read from HBM exactly once. Scores via MFMA (A=ctx chunk, B=qp regs),
// online softmax per chunk, PV via VALU from the same LDS chunk.
__global__ __launch_bounds__(256, 2) void k_flash2(
    const float* __restrict__ ctx, const unsigned short* __restrict__ qpb,
    const float* __restrict__ sb, const float* __restrict__ dist,
    const int* __restrict__ mask, float* __restrict__ partA,
    float* __restrict__ partM, float* __restrict__ partL, int N) {
    __shared__ unsigned short cbuf[2][CHW][CBSTR];  // 66048 B
    __shared__ float red[4][CHW][17];               // 4352 B
    __shared__ float P_lds[CHW][20];                // 1280 B
    __shared__ float fh_lds[NH];
    __shared__ float dls[BROW];

    int b = blockIdx.x, ns = blockIdx.y;
    int t = threadIdx.x, lane = t & 63, w = t >> 6;
    int m = lane & 15, g = lane >> 4;
    int nb0 = ns * BROW;
    int NIT = BROW / CHW;  // 16

    // preload dist+mask for the block's row range
    {
        float dv = dist[(size_t)b * N + nb0 + t] * DLAM;
        dls[t] = mask[(size_t)b * N + nb0 + t] ? dv : -1e30f;
    }
    // preload qp B-fragments (wave w covers K-slice [w*256, w*256+256))
    bf16x8 qf[8];
#pragma unroll
    for (int j = 0; j < 8; ++j)
        qf[j] = *reinterpret_cast<const bf16x8*>(
            qpb + ((size_t)(b * NH + m)) * DDIM + w * 256 + j * 32 + g * 8);
    float sbv = sb[b * NH + m];

    f32x4 acc[NH];
#pragma unroll
    for (int h = 0; h < NH; ++h) acc[h] = (f32x4){0.f, 0.f, 0.f, 0.f};
    float m_run = -1e30f, l_run = 0.f;

    const float4* cb4 = reinterpret_cast<const float4*>(ctx) +
                        ((size_t)b * N + nb0) * (DDIM / 4);
    float4 inflight[16];

#define LOADC(c)                                               \
    {                                                          \
        const float4* src = cb4 + (size_t)(c) * CHW * (DDIM / 4); \
        _Pragma("unroll") for (int i = 0; i < 16; ++i)         \
            inflight[i] = src[i * 256 + t];                    \
    }
#define WRITECB(buf)                                                        \
    {                                                                       \
        _Pragma("unroll") for (int i = 0; i < 16; ++i) {                    \
            float4 v = inflight[i];                                         \
            unsigned lo = (unsigned)f2bf(v.x) | ((unsigned)f2bf(v.y) << 16);\
            unsigned hi = (unsigned)f2bf(v.z) | ((unsigned)f2bf(v.w) << 16);\
            *reinterpret_cast<uint2*>(&cbuf[buf][i][t * 4]) =               \
                make_uint2(lo, hi);                                         \
        }                                                                   \
    }

    LOADC(0);
    WRITECB(0);
    LOADC(1);

    for (int c = 0; c < NIT; ++c) {
        __syncthreads();  // A: cbuf[buf] visible
        int buf = c & 1;
        // ---- scores (wave K-slice 256) ----
        f32x4 cS = {0.f, 0.f, 0.f, 0.f};
#pragma unroll
        for (int j = 0; j < 8; ++j) {
            bf16x8 a = *reinterpret_cast<const bf16x8*>(
                &cbuf[buf][m][w * 256 + j * 32 + g * 8]);
            cS = __builtin_amdgcn_mfma_f32_16x16x32_bf16(a, qf[j], cS, 0, 0, 0);
        }
#pragma unroll
        for (int r = 0; r < 4; ++r) red[w][g * 4 + r][m] = cS[r];
        __syncthreads();  // B: partials ready
        float S[4];
#pragma unroll
        for (int r = 0; r < 4; ++r) {
            int n = g * 4 + r;
            S[r] = red[0][n][m] + red[1][n][m] + red[2][n][m] + red[3][n][m] +
                   sbv + dls[c * CHW + n];
        }
        float cm = fmaxf(fmaxf(S[0], S[1]), fmaxf(S[2], S[3]));
        cm = fmaxf(cm, __shfl_xor(cm, 16, 64));
        cm = fmaxf(cm, __shfl_xor(cm, 32, 64));
        float mnew = fmaxf(m_run, cm);
        float f = __expf(m_run - mnew);
        float p[4];
        float ls = 0.f;
#pragma unroll
        for (int r = 0; r < 4; ++r) {
            p[r] = __expf(S[r] - mnew);
            ls += p[r];
        }
        ls += __shfl_xor(ls, 16, 64);
        ls += __shfl_xor(ls, 32, 64);
        l_run = l_run * f + ls;
        m_run = mnew;
#pragma unroll
        for (int r = 0; r < 4; ++r) P_lds[g * 4 + r][m] = p[r];
        if (w == 0 && g == 0) fh_lds[m] = f;
        __syncthreads();  // C: P and f ready
        // ---- PV (VALU) ----
#pragma unroll
        for (int h = 0; h < NH; ++h) acc[h] *= fh_lds[h];
        int dq = w * 256 + lane * 4;  // this lane's d-quad
#pragma unroll 4
        for (int n = 0; n < CHW; ++n) {
            uint2 cw = *reinterpret_cast<const uint2*>(&cbuf[buf][n][dq]);
            float cv0 = bflo2f(cw.x), cv1 = bfhi2f(cw.x);
            float cv2 = bflo2f(cw.y), cv3 = bfhi2f(cw.y);
            float4 P0 = *reinterpret_cast<const float4*>(&P_lds[n][0]);
            float4 P1 = *reinterpret_cast<const float4*>(&P_lds[n][4]);
            float4 P2 = *reinterpret_cast<const float4*>(&P_lds[n][8]);
            float4 P3 = *reinterpret_cast<const float4*>(&P_lds[n][12]);
            float Pv[16] = {P0.x, P0.y, P0.z, P0.w, P1.x, P1.y, P1.z, P1.w,
                            P2.x, P2.y, P2.z, P2.w, P3.x, P3.y, P3.z, P3.w};
#pragma unroll
            for (int h = 0; h < NH; ++h) {
                acc[h][0] = fmaf(Pv[h], cv0, acc[h][0]);
                acc[h][1] = fmaf(Pv[h], cv1, acc[h][1]);
                acc[h][2] = fmaf(Pv[h], cv2, acc[h][2]);
                acc[h][3] = fmaf(Pv[h], cv3, acc[h][3]);
            }
        }
        __syncthreads();  // D: done reading cbuf[buf]/P_lds/red
        if (c + 1 < NIT) {
            WRITECB(buf ^ 1);
            if (c + 2 < NIT) LOADC(c + 2);
        }
    }

    // epilogue: write per-block partials
    int dq = w * 256 + lane * 4;
#pragma unroll
    for (int h = 0; h < NH; ++h) {
        float4 o = make_float4(acc[h][0], acc[h][1], acc[h][2], acc[h][3]);
        *reinterpret_cast<float4*>(
            partA + ((size_t)((b * NS + ns) * NH + h)) * DDIM + dq) = o;
    }
    if (t < NH) {
        partM[(b * NS + ns) * NH + t] = m_run;
        partL[(b * NS + ns) * NH + t] = l_run;
    }
#undef LOADC
#undef WRITECB
}

// K4: merge chunk partials -> ctxa[b,h,d]
__global__ __launch_bounds__(256) void k_comb(const float* __restrict__ partA,
                                              const float* __restrict__ partM,
                                              const float* __restrict__ partL,
                                              float* __restrict__ ctxa) {
    int row = blockIdx.x;  // b*NH + h
    int b = row >> 4, h = row & 15;
    float M = -1e30f;
#pragma unroll
    for (int ns = 0; ns < NS; ++ns)
        M = fmaxf(M, partM[(b * NS + ns) * NH + h]);
    float denom = 0.f;
#pragma unroll
    for (int ns = 0; ns < NS; ++ns)
        denom = fmaf(__expf(partM[(b * NS + ns) * NH + h] - M),
                     partL[(b * NS + ns) * NH + h], denom);
    float inv = 1.f / denom;
    int d4 = threadIdx.x * 4;
    float4 a = make_float4(0.f, 0.f, 0.f, 0.f);
#pragma unroll 8
    for (int ns = 0; ns < NS; ++ns) {
        float wv = __expf(partM[(b * NS + ns) * NH + h] - M);
        float4 v = *reinterpret_cast<const float4*>(
            partA + ((size_t)((b * NS + ns) * NH + h)) * DDIM + d4);
        a.x = fmaf(wv, v.x, a.x);
        a.y = fmaf(wv, v.y, a.y);
        a.z = fmaf(wv, v.z, a.z);
        a.w = fmaf(wv, v.w, a.w);
    }
    float4 o = make_float4(a.x * inv, a.y * inv, a.z * inv, a.w * inv);
    *reinterpret_cast<float4*>(ctxa + (size_t)row * DDIM + d4) = o;
}

// K5: oattn[b,c] = ctxa[b, c>>6, :] . Wv[:, c] + bv[c]; grid (B, 8)
__global__ __launch_bounds__(256) void k_vproj(const float* __restrict__ ctxa,
                                               const float* __restrict__ Wv,
                                               const float* __restrict__ bv,
                                               float* __restrict__ oattn) {
    int b = blockIdx.x, c0 = blockIdx.y * 128;
    int h0 = c0 >> 6;
    __shared__ float cs[2][DDIM];
    __shared__ float ps[256];
    for (int i = threadIdx.x; i < 2 * DDIM; i += 256)
        cs[i >> 10][i & 1023] =
            ctxa[((size_t)(b * NH + h0 + (i >> 10))) * DDIM + (i & 1023)];
    __syncthreads();
    int t = threadIdx.x;
    int cl = t & 127;
    int col = c0 + cl;
    int hl = cl >> 6;
    int d0 = (t >> 7) * 512;
    float acc = 0.f;
#pragma unroll 8
    for (int d = d0; d < d0 + 512; ++d)
        acc = fmaf(cs[hl][d], Wv[(size_t)d * DDIM + col], acc);
    ps[t] = acc;
    __syncthreads();
    if (t < 128) oattn[b * DDIM + col] = ps[t] + ps[t + 128] + bv[col];
}

// K6: x[b,c] = query[b,c] + oattn[b,:] . Wo[:,c] + bo[c]; grid (B, 8)
__global__ __launch_bounds__(256) void k_oproj(const float* __restrict__ query,
                                               const float* __restrict__ oattn,
                                               const float* __restrict__ Wo,
                                               const float* __restrict__ bo,
                                               float* __restrict__ x) {
    int b = blockIdx.x, c0 = blockIdx.y * 128;
    __shared__ float os[DDIM];
    __shared__ float ps[256];
    for (int i = threadIdx.x; i < DDIM; i += 256) os[i] = oattn[b * DDIM + i];
    __syncthreads();
    int t = threadIdx.x;
    int col = c0 + (t & 127);
    int d0 = (t >> 7) * 512;
    float acc = 0.f;
#pragma unroll 8
    for (int d = d0; d < d0 + 512; ++d)
        acc = fmaf(os[d], Wo[(size_t)d * DDIM + col], acc);
    ps[t] = acc;
    __syncthreads();
    if (t < 128)
        x[b * DDIM + col] = query[b * DDIM + col] + ps[t] + ps[t + 128] + bo[col];
}

// K7: out = LayerNorm(x) * gamma + beta; grid B
__global__ __launch_bounds__(256) void k_ln(const float* __restrict__ x,
                                            const float* __restrict__ gamma,
                                            const float* __restrict__ beta,
                                            float* __restrict__ out) {
    int b = blockIdx.x;
    int t = threadIdx.x;
    __shared__ float red[8];
    float xv[4];
    float lsum = 0.f;
#pragma unroll
    for (int k = 0; k < 4; ++k) {
        xv[k] = x[b * DDIM + t + k * 256];
        lsum += xv[k];
    }
#pragma unroll
    for (int off = 32; off > 0; off >>= 1) lsum += __shfl_xor(lsum, off, 64);
    if ((t & 63) == 0) red[t >> 6] = lsum;
    __syncthreads();
    float mu = (red[0] + red[1] + red[2] + red[3]) * (1.f / DDIM);
    float lsq = 0.f;
#pragma unroll
    for (int k = 0; k < 4; ++k) {
        float dx = xv[k] - mu;
        lsq += dx * dx;
    }
#pragma unroll
    for (int off = 32; off > 0; off >>= 1) lsq += __shfl_xor(lsq, off, 64);
    if ((t & 63) == 0) red[4 + (t >> 6)] = lsq;
    __syncthreads();
    float var = (red[4] + red[5] + red[6] + red[7]) * (1.f / DDIM);
    float rstd = rsqrtf(var + LNEPS);
#pragma unroll
    for (int k = 0; k < 4; ++k) {
        int c = t + k * 256;
        out[b * DDIM + c] = (xv[k] - mu) * rstd * gamma[c] + beta[c];
    }
}

extern "C" void kernel_launch(void* const* d_in, const int* in_sizes, int n_in,
                              void* d_out, int out_size, void* d_ws, size_t ws_size,
                              hipStream_t stream) {
    const float* query = (const float*)d_in[0];
    const float* ctx   = (const float*)d_in[1];
    const float* dist  = (const float*)d_in[2];
    const int*   mask  = (const int*)d_in[3];
    const float* Wq = (const float*)d_in[4];
    const float* bq = (const float*)d_in[5];
    const float* Wk = (const float*)d_in[6];
    const float* bk = (const float*)d_in[7];
    const float* Wv = (const float*)d_in[8];
    const float* bv = (const float*)d_in[9];
    const float* Wo = (const float*)d_in[10];
    const float* bo = (const float*)d_in[11];
    const float* gamma = (const float*)d_in[12];
    const float* beta  = (const float*)d_in[13];
    float* out = (float*)d_out;

    int B = in_sizes[0] / DDIM;        // 32
    int N = in_sizes[1] / (B * DDIM);  // 4096

    float* ws = (float*)d_ws;
    float* q = ws;                                                      // B*D
    unsigned short* qpb = (unsigned short*)(q + (size_t)B * DDIM);      // B*NH*D bf16
    float* sb = (float*)(qpb + (size_t)B * NH * DDIM);                  // B*NH
    float* partA = sb + (size_t)B * NH;                                 // B*NS*NH*D
    float* partM = partA + (size_t)B * NS * NH * DDIM;                  // B*NS*NH
    float* partL = partM + (size_t)B * NS * NH;                         // B*NS*NH
    float* ctxa = partL + (size_t)B * NS * NH;                          // B*NH*D
    float* oattn = ctxa + (size_t)B * NH * DDIM;                        // B*D
    float* xbuf = oattn + (size_t)B * DDIM;                             // B*D

    k_q<<<dim3(B, 8), 512, 0, stream>>>(query, Wq, bq, q);
    k_qp<<<dim3(B, DDIM / 16), 256, 0, stream>>>(q, Wk, qpb);
    k_sb<<<1, B * NH, 0, stream>>>(q, bk, sb);
    k_flash2<<<dim3(B, NS), 256, 0, stream>>>(ctx, qpb, sb, dist, mask,
                                              partA, partM, partL, N);
    k_comb<<<B * NH, 256, 0, stream>>>(partA, partM, partL, ctxa);
    k_vproj<<<dim3(B, 8), 256, 0, stream>>>(ctxa, Wv, bv, oattn);
    k_oproj<<<dim3(B, 8), 256, 0, stream>>>(query, oattn, Wo, bo, xbuf);
    k_ln<<<B, 256, 0, stream>>>(xbuf, gamma, beta, out);
}